// Round 3
// baseline (115.779 us; speedup 1.0000x reference)
//
#include <hip/hip_runtime.h>

#define NI 64
#define NJ 8192
#define NK 128

// workspace float offsets
#define WS_M    0         // M[kp][k] = sum_c Wk[c][kp]*Wq[c][k]   (16384)
#define WS_WVT  16384     // WvT[kp][c] = Wv[c][kp]                (16384)
#define WS_D    32768     // d[k] = sum_c Wq[c][k]*bk[c]           (128)
#define WS_KQ   32896     // kq[j][k]                              (NJ*NK)

// ---------------- K1: tiny precompute of M, WvT, d ----------------
__global__ __launch_bounds__(128) void precompute_kernel(
    const float* __restrict__ Wv, const float* __restrict__ Wq,
    const float* __restrict__ Wk, const float* __restrict__ bk,
    float* __restrict__ ws)
{
    const int b = blockIdx.x;    // kp
    const int k = threadIdx.x;   // k
    float macc = 0.f, dacc = 0.f;
    for (int c = 0; c < NK; ++c) {
        float wq = Wq[c*NK + k];          // coalesced
        macc += Wk[c*NK + b] * wq;        // Wk col: uniform per block
        if (b == 0) dacc += bk[c] * wq;
    }
    ws[WS_M + b*NK + k] = macc;
    ws[WS_WVT + b*NK + k] = Wv[k*NK + b];
    if (b == 0) ws[WS_D + k] = dacc;
}

// ---------------- K2: kq[j,k] = d[k] + sum_kp x3[j,kp]*M[kp,k] ----------------
__global__ __launch_bounds__(256) void kq_kernel(
    const float* __restrict__ x, const int* __restrict__ pIdx,
    const float* __restrict__ ws, float* __restrict__ kqout)
{
    const int tid = threadIdx.x;
    const int k2  = tid & 63;          // k-pair index: k in {2k2, 2k2+1}
    const int wv  = tid >> 6;
    const int j0  = blockIdx.x * 16 + wv * 4;
    const int idx = *pIdx;
    const float* __restrict__ M  = ws + WS_M;
    const float* __restrict__ x3 = x + (size_t)idx * NJ * NK;

    const float* r0 = x3 + (size_t)(j0+0)*NK;
    const float* r1 = x3 + (size_t)(j0+1)*NK;
    const float* r2 = x3 + (size_t)(j0+2)*NK;
    const float* r3 = x3 + (size_t)(j0+3)*NK;

    float d0 = ws[WS_D + 2*k2], d1 = ws[WS_D + 2*k2 + 1];
    float2 acc[4];
#pragma unroll
    for (int jj = 0; jj < 4; ++jj) { acc[jj].x = d0; acc[jj].y = d1; }

#pragma unroll 2
    for (int kp = 0; kp < NK; kp += 4) {
        float4 x0 = *(const float4*)(r0 + kp);   // uniform per wave -> broadcast
        float4 x1 = *(const float4*)(r1 + kp);
        float4 x2 = *(const float4*)(r2 + kp);
        float4 x3v = *(const float4*)(r3 + kp);
        float2 m0 = *(const float2*)(M + (kp+0)*NK + 2*k2);  // coalesced
        float2 m1 = *(const float2*)(M + (kp+1)*NK + 2*k2);
        float2 m2 = *(const float2*)(M + (kp+2)*NK + 2*k2);
        float2 m3 = *(const float2*)(M + (kp+3)*NK + 2*k2);
        acc[0].x += x0.x*m0.x + x0.y*m1.x + x0.z*m2.x + x0.w*m3.x;
        acc[0].y += x0.x*m0.y + x0.y*m1.y + x0.z*m2.y + x0.w*m3.y;
        acc[1].x += x1.x*m0.x + x1.y*m1.x + x1.z*m2.x + x1.w*m3.x;
        acc[1].y += x1.x*m0.y + x1.y*m1.y + x1.z*m2.y + x1.w*m3.y;
        acc[2].x += x2.x*m0.x + x2.y*m1.x + x2.z*m2.x + x2.w*m3.x;
        acc[2].y += x2.x*m0.y + x2.y*m1.y + x2.z*m2.y + x2.w*m3.y;
        acc[3].x += x3v.x*m0.x + x3v.y*m1.x + x3v.z*m2.x + x3v.w*m3.x;
        acc[3].y += x3v.x*m0.y + x3v.y*m1.y + x3v.z*m2.y + x3v.w*m3.y;
    }
#pragma unroll
    for (int jj = 0; jj < 4; ++jj)
        *(float2*)(kqout + (size_t)(j0+jj)*NK + 2*k2) = acc[jj];
}

// ---------------- K3: att + online softmax + y; one wave per j, no LDS, no barriers ----------------
__global__ __launch_bounds__(256, 4) void att_y_kernel(
    const float* __restrict__ x, const float* __restrict__ kq,
    float* __restrict__ y)
{
    const int tid  = threadIdx.x;
    const int lane = tid & 63;
    const int wave = tid >> 6;
    const int half = lane >> 5;          // rows 0..31 vs 32..63
    const int lq   = lane & 31;
    const int k0   = lq * 4;             // k coverage: float4 per lane
    const int j    = blockIdx.x * 4 + wave;
    const size_t ISTEP = (size_t)NJ * NK;

    // lane's stream base: row half*32, this j, this k-slice
    const float* xb = x + (size_t)(half * 32) * ISTEP + (size_t)j * NK + k0;
    const float4 kqv = *(const float4*)(kq + (size_t)j * NK + k0);

    float4 A[8], B[8];
    auto ld = [&](int r0, float4 (&buf)[8]) {
#pragma unroll
        for (int t = 0; t < 8; ++t)
            buf[t] = *(const float4*)(xb + (size_t)(r0 + t) * ISTEP);
    };

    float m = -3.0e38f, s = 0.f;
    float4 yacc = make_float4(0.f, 0.f, 0.f, 0.f);

    auto proc = [&](float4 (&buf)[8]) {
        float p[8];
#pragma unroll
        for (int t = 0; t < 8; ++t)
            p[t] = buf[t].x*kqv.x + buf[t].y*kqv.y + buf[t].z*kqv.z + buf[t].w*kqv.w;
        // reduce each row-logit over the 32-lane half (k dimension)
#pragma unroll
        for (int t = 0; t < 8; ++t) {
            p[t] += __shfl_xor(p[t], 1);
            p[t] += __shfl_xor(p[t], 2);
            p[t] += __shfl_xor(p[t], 4);
            p[t] += __shfl_xor(p[t], 8);
            p[t] += __shfl_xor(p[t], 16);
        }
        float cm = fmaxf(fmaxf(fmaxf(p[0],p[1]), fmaxf(p[2],p[3])),
                         fmaxf(fmaxf(p[4],p[5]), fmaxf(p[6],p[7])));
        float mn = fmaxf(m, cm);
        float sc = __expf(m - mn);       // first chunk: exp(-huge) = 0
        s *= sc;
        yacc.x *= sc; yacc.y *= sc; yacc.z *= sc; yacc.w *= sc;
#pragma unroll
        for (int t = 0; t < 8; ++t) {
            float e = __expf(p[t] - mn);
            s += e;
            yacc.x += e * buf[t].x; yacc.y += e * buf[t].y;
            yacc.z += e * buf[t].z; yacc.w += e * buf[t].w;
        }
        m = mn;
    };

    ld(0, A);
    ld(8, B);
    proc(A);
    ld(16, A);
    proc(B);
    ld(24, B);
    proc(A);
    proc(B);

    // merge the two 32-row halves across lane^32
    float m_o = __shfl_xor(m, 32);
    float s_o = __shfl_xor(s, 32);
    float4 y_o;
    y_o.x = __shfl_xor(yacc.x, 32);
    y_o.y = __shfl_xor(yacc.y, 32);
    y_o.z = __shfl_xor(yacc.z, 32);
    y_o.w = __shfl_xor(yacc.w, 32);
    float M  = fmaxf(m, m_o);
    float es = __expf(m - M), eo = __expf(m_o - M);
    float S  = s * es + s_o * eo;
    float inv = 1.f / S;
    float4 yf;
    yf.x = (yacc.x * es + y_o.x * eo) * inv;
    yf.y = (yacc.y * es + y_o.y * eo) * inv;
    yf.z = (yacc.z * es + y_o.z * eo) * inv;
    yf.w = (yacc.w * es + y_o.w * eo) * inv;
    if (half == 0)
        *(float4*)(y + (size_t)j * NK + k0) = yf;
}

// ---------------- K4: feat[j,c] = bv[c] + sum_kp y[j,kp]*WvT[kp,c] (in-place in d_out) ----------------
__global__ __launch_bounds__(256) void feat_kernel(
    float* __restrict__ yio, const float* __restrict__ bv,
    const float* __restrict__ ws)
{
    const int tid = threadIdx.x;
    const int k2  = tid & 63;
    const int wv  = tid >> 6;
    const int j0  = blockIdx.x * 16 + wv * 4;
    const float* __restrict__ W = ws + WS_WVT;

    const float* r0 = yio + (size_t)(j0+0)*NK;
    const float* r1 = yio + (size_t)(j0+1)*NK;
    const float* r2 = yio + (size_t)(j0+2)*NK;
    const float* r3 = yio + (size_t)(j0+3)*NK;

    float b0 = bv[2*k2], b1 = bv[2*k2 + 1];
    float2 acc[4];
#pragma unroll
    for (int jj = 0; jj < 4; ++jj) { acc[jj].x = b0; acc[jj].y = b1; }

#pragma unroll 2
    for (int kp = 0; kp < NK; kp += 4) {
        float4 x0 = *(const float4*)(r0 + kp);
        float4 x1 = *(const float4*)(r1 + kp);
        float4 x2 = *(const float4*)(r2 + kp);
        float4 x3v = *(const float4*)(r3 + kp);
        float2 m0 = *(const float2*)(W + (kp+0)*NK + 2*k2);
        float2 m1 = *(const float2*)(W + (kp+1)*NK + 2*k2);
        float2 m2 = *(const float2*)(W + (kp+2)*NK + 2*k2);
        float2 m3 = *(const float2*)(W + (kp+3)*NK + 2*k2);
        acc[0].x += x0.x*m0.x + x0.y*m1.x + x0.z*m2.x + x0.w*m3.x;
        acc[0].y += x0.x*m0.y + x0.y*m1.y + x0.z*m2.y + x0.w*m3.y;
        acc[1].x += x1.x*m0.x + x1.y*m1.x + x1.z*m2.x + x1.w*m3.x;
        acc[1].y += x1.x*m0.y + x1.y*m1.y + x1.z*m2.y + x1.w*m3.y;
        acc[2].x += x2.x*m0.x + x2.y*m1.x + x2.z*m2.x + x2.w*m3.x;
        acc[2].y += x2.x*m0.y + x2.y*m1.y + x2.z*m2.y + x2.w*m3.y;
        acc[3].x += x3v.x*m0.x + x3v.y*m1.x + x3v.z*m2.x + x3v.w*m3.x;
        acc[3].y += x3v.x*m0.y + x3v.y*m1.y + x3v.z*m2.y + x3v.w*m3.y;
    }
    // rows j0..j0+3 are read fully before overwrite by this same wave -> in-place safe
#pragma unroll
    for (int jj = 0; jj < 4; ++jj)
        *(float2*)(yio + (size_t)(j0+jj)*NK + 2*k2) = acc[jj];
}

extern "C" void kernel_launch(void* const* d_in, const int* in_sizes, int n_in,
                              void* d_out, int out_size, void* d_ws, size_t ws_size,
                              hipStream_t stream) {
    const float* x  = (const float*)d_in[0];
    const float* Wv = (const float*)d_in[1];
    const float* bv = (const float*)d_in[2];
    const float* Wq = (const float*)d_in[3];
    const float* bq = (const float*)d_in[4];  (void)bq;  // cancels in softmax over agents
    const float* Wk = (const float*)d_in[5];
    const float* bk = (const float*)d_in[6];
    const int*  idx = (const int*)d_in[7];
    float* ws  = (float*)d_ws;
    float* out = (float*)d_out;

    precompute_kernel<<<NK, NK, 0, stream>>>(Wv, Wq, Wk, bk, ws);
    kq_kernel<<<NJ/16, 256, 0, stream>>>(x, idx, ws, ws + WS_KQ);
    att_y_kernel<<<NJ/4, 256, 0, stream>>>(x, ws + WS_KQ, out);    // out holds y
    feat_kernel<<<NJ/16, 256, 0, stream>>>(out, bv, ws);           // in-place y->feat
}